// Round 2
// baseline (82.149 us; speedup 1.0000x reference)
//
#include <hip/hip_runtime.h>

// DNM dendritic layer: out[b,o] = max(0, 0.25*S - 0.05),
//   S = sum_{m,i} relu(x[b,i]*W[o,m,i] - q[o,m,i])
// B=512, OUT=128, M=8, IN=512, fp32 in/out.
//
// R13: consolidation at the issue floor. R10-R12 invariance (77.7-78.9
// across occupancy x2, instr-mix ~10%, L2 traffic 6x) proves the kernel
// is issue-bound at the 3-VALU-per-h2 floor (pk_fma + pk_max + 1
// amortized accumulate; 6.29M wave-instrs total) behind a fixed 42us
// harness fill. This round removes the last bookkeeping: single kernel
// (no cvt pre-pass, saves a graph node + gap), v_cvt_pkrtz staging
// (1 instr/h2 vs ~3 for RNE cvt+pack; absmax headroom 4.6x), R12's
// 3-add+1-dot2 accumulation tree. Tile: 1 o x 32 b per block (8 b/thread),
// grid 128*16=2048, LDS 16 KB, VGPR ~75.

#define OUTN 128
#define MM   8
#define INN  512
#define BB   512

typedef float    f4 __attribute__((ext_vector_type(4)));
typedef _Float16 h2 __attribute__((ext_vector_type(2)));
typedef _Float16 h4 __attribute__((ext_vector_type(4)));
typedef _Float16 h8 __attribute__((ext_vector_type(8)));

__device__ __forceinline__ h2 pkrtz(float a, float b)
{
#if __has_builtin(__builtin_amdgcn_cvt_pkrtz)
    auto t = __builtin_amdgcn_cvt_pkrtz(a, b);   // v_cvt_pkrtz_f16_f32
    return (h2){(_Float16)t[0], (_Float16)t[1]};
#else
    return (h2){(_Float16)a, (_Float16)b};
#endif
}

// Block: 256 threads = 4 waves, one o, 32 b's (8/wave). Lane owns i0=lane*8.
// Grid: 128 o * 16 b-groups = 2048 blocks. LDS 16 KB.
__global__ __launch_bounds__(256) void dnm_kernel(
    const float* __restrict__ x,   // [B, IN]  fp32
    const float* __restrict__ W,   // [OUT, M, IN]  fp32
    const float* __restrict__ q,   // [OUT, M, IN]  fp32
    float* __restrict__ out)       // [B, OUT]
{
    __shared__ _Float16 lw[MM * INN];   // 8 KB
    __shared__ _Float16 lq[MM * INN];   // 8 KB

    const int tid  = threadIdx.x;
    const int o    = blockIdx.x >> 4;
    const int bgrp = blockIdx.x & 15;
    const int wave = tid >> 6;
    const int lane = tid & 63;
    const int b0   = bgrp * 32 + wave * 8;
    const int i0   = lane * 8;

    // Stage W[o], q[o]: 4096 f32 each; 4 f4-groups per thread per array.
    // pkrtz: 2 instrs per h4 (vs ~6 for RNE cvt+pack).
    {
        const f4* Wg = (const f4*)(W + (size_t)o * MM * INN);
        const f4* qg = (const f4*)(q + (size_t)o * MM * INN);
        h4* lwv = (h4*)lw;
        h4* lqv = (h4*)lq;
        #pragma unroll
        for (int c = 0; c < 4; ++c) {
            const int j = tid + c * 256;
            f4 a = Wg[j];
            f4 b = qg[j];
            h2 a01 = pkrtz(a[0], a[1]);
            h2 a23 = pkrtz(a[2], a[3]);
            h2 b01 = pkrtz(b[0], b[1]);
            h2 b23 = pkrtz(b[2], b[3]);
            lwv[j] = (h4){a01[0], a01[1], a23[0], a23[1]};
            lqv[j] = (h4){b01[0], b01[1], b23[0], b23[1]};
        }
    }

    // This wave's 8 x-rows, converted in-flight (overlaps other waves'
    // staging; before the barrier). 32 VGPRs resident.
    h8 xv[8];
    #pragma unroll
    for (int b = 0; b < 8; ++b) {
        const float* xr = x + (size_t)(b0 + b) * INN + i0;
        f4 lo = *(const f4*)xr;
        f4 hi = *(const f4*)(xr + 4);
        h2 p0 = pkrtz(lo[0], lo[1]);
        h2 p1 = pkrtz(lo[2], lo[3]);
        h2 p2 = pkrtz(hi[0], hi[1]);
        h2 p3 = pkrtz(hi[2], hi[3]);
        xv[b] = (h8){p0[0], p0[1], p1[0], p1[1], p2[0], p2[1], p3[0], p3[1]};
    }

    __syncthreads();

    float acc[8];
    #pragma unroll
    for (int b = 0; b < 8; ++b) acc[b] = 0.0f;

    const h2 one  = {(_Float16)1.0f, (_Float16)1.0f};
    const h2 zero = (h2)(_Float16)0.0f;

    // unroll 2: two m's of fragments live (16 VGPRs), not all 8.
    #pragma unroll 2
    for (int m = 0; m < MM; ++m) {
        const h8 w8 = *(const h8*)(lw + m * INN + i0);
        const h8 q8 = *(const h8*)(lq + m * INN + i0);
        #pragma unroll
        for (int b = 0; b < 8; ++b) {
            // 4x (pk_fma + pk_max) + 3 pk_add + 1 dot2 = 12 VALU / 8 elems
            // = the 3-per-h2 floor (fma, relu, amortized accumulate).
            h2 t0, t1, t2, t3;
            {
                h2 xx = __builtin_shufflevector(xv[b], xv[b], 0, 1);
                h2 ww = __builtin_shufflevector(w8, w8, 0, 1);
                h2 qq = __builtin_shufflevector(q8, q8, 0, 1);
                t0 = __builtin_elementwise_max(__builtin_elementwise_fma(xx, ww, -qq), zero);
            }
            {
                h2 xx = __builtin_shufflevector(xv[b], xv[b], 2, 3);
                h2 ww = __builtin_shufflevector(w8, w8, 2, 3);
                h2 qq = __builtin_shufflevector(q8, q8, 2, 3);
                t1 = __builtin_elementwise_max(__builtin_elementwise_fma(xx, ww, -qq), zero);
            }
            {
                h2 xx = __builtin_shufflevector(xv[b], xv[b], 4, 5);
                h2 ww = __builtin_shufflevector(w8, w8, 4, 5);
                h2 qq = __builtin_shufflevector(q8, q8, 4, 5);
                t2 = __builtin_elementwise_max(__builtin_elementwise_fma(xx, ww, -qq), zero);
            }
            {
                h2 xx = __builtin_shufflevector(xv[b], xv[b], 6, 7);
                h2 ww = __builtin_shufflevector(w8, w8, 6, 7);
                h2 qq = __builtin_shufflevector(q8, q8, 6, 7);
                t3 = __builtin_elementwise_max(__builtin_elementwise_fma(xx, ww, -qq), zero);
            }
            h2 s = (t0 + t1) + (t2 + t3);
#if __has_builtin(__builtin_amdgcn_fdot2)
            acc[b] = __builtin_amdgcn_fdot2(s, one, acc[b], false);
#else
            acc[b] += (float)s[0] + (float)s[1];
#endif
        }
    }

    // Butterfly-reduce each acc[b] across 64 lanes; lane b writes (b0+b, o).
    #pragma unroll
    for (int b = 0; b < 8; ++b) {
        float v = acc[b];
        v += __shfl_xor(v, 1, 64);
        v += __shfl_xor(v, 2, 64);
        v += __shfl_xor(v, 4, 64);
        v += __shfl_xor(v, 8, 64);
        v += __shfl_xor(v, 16, 64);
        v += __shfl_xor(v, 32, 64);
        if (lane == b) {
            float r = 0.25f * v - 0.05f;   // K*K*S - K*QS
            out[(size_t)(b0 + b) * OUTN + o] = fmaxf(r, 0.0f);
        }
    }
}

extern "C" void kernel_launch(void* const* d_in, const int* in_sizes, int n_in,
                              void* d_out, int out_size, void* d_ws, size_t ws_size,
                              hipStream_t stream)
{
    const float* x = (const float*)d_in[0];
    const float* W = (const float*)d_in[1];
    const float* q = (const float*)d_in[2];
    float* out = (float*)d_out;
    dim3 grid(OUTN * 16);   // 128 o * 16 b-groups = 2048 blocks
    dim3 block(256);
    dnm_kernel<<<grid, block, 0, stream>>>(x, W, q, out);
}

// Round 3
// 77.422 us; speedup vs baseline: 1.0611x; 1.0611x over previous
//
#include <hip/hip_runtime.h>

// DNM dendritic layer: out[b,o] = max(0, 0.25*S - 0.05),
//   S = sum_{m,i} relu(fma(x[b,i], W[o,m,i], -q[o,m,i]))
// B=512, OUT=128, M=8, IN=512, fp32 in/out.
//
// R14 = R11 (best verified, 77.7us) + v_cvt_pkrtz staging from R13.
// R10-R13 ledger: 77.9/77.7/78.9/82.1. Total is fill (41us @82% HBM,
// harness-fixed) + kernel residual invariant to occupancy x2, instr
// count +-15%, L2 traffic x6, launch count. Only negative lever found:
// cutting wave count (R13). So: revert to R11's full-occupancy layout
// (4 b/thread, VGPR<=64, grid 4096 = two fully-resident generations of
// 32 waves/CU), keep only the strictly-positive pkrtz micro-change
// (2 instrs/f4 vs ~6 RNE cvt+pack; RTZ ok, absmax headroom 4.6x).

#define OUTN 128
#define MM   8
#define INN  512

typedef float    f4 __attribute__((ext_vector_type(4)));
typedef _Float16 h2 __attribute__((ext_vector_type(2)));
typedef _Float16 h4 __attribute__((ext_vector_type(4)));
typedef _Float16 h8 __attribute__((ext_vector_type(8)));

__device__ __forceinline__ h2 pkrtz(float a, float b)
{
#if __has_builtin(__builtin_amdgcn_cvt_pkrtz)
    auto t = __builtin_amdgcn_cvt_pkrtz(a, b);   // v_cvt_pkrtz_f16_f32
    return (h2){(_Float16)t[0], (_Float16)t[1]};
#else
    return (h2){(_Float16)a, (_Float16)b};
#endif
}

// Block: 256 threads = 4 waves, one o, 16 b's (4/wave).
// Grid: 128 o * 32 b-groups = 4096 blocks. LDS 16 KB.
__global__ __launch_bounds__(256) void dnm_kernel(
    const float* __restrict__ x,   // [B, IN]  fp32
    const float* __restrict__ W,   // [OUT, M, IN]  fp32
    const float* __restrict__ q,   // [OUT, M, IN]  fp32
    float* __restrict__ out)       // [B, OUT]
{
    __shared__ _Float16 lds_w[MM * INN];   // 8 KB
    __shared__ _Float16 lds_q[MM * INN];   // 8 KB

    const int tid  = threadIdx.x;
    const int o    = blockIdx.x >> 5;
    const int bgrp = blockIdx.x & 31;
    const int wave = tid >> 6;
    const int lane = tid & 63;
    const int b0   = bgrp * 16 + wave * 4;
    const int i0   = lane * 8;             // this lane's 8 i's

    // Stage W[o], q[o]: load f32 (coalesced f4), pkrtz to h4, store.
    {
        const f4* Wg = (const f4*)(W + (size_t)o * MM * INN);
        const f4* qg = (const f4*)(q + (size_t)o * MM * INN);
        h4* lw = (h4*)lds_w;
        h4* lq = (h4*)lds_q;
        #pragma unroll
        for (int c = 0; c < 4; ++c) {
            const int j = tid + c * 256;
            f4 a = Wg[j];
            f4 b = qg[j];
            h2 a01 = pkrtz(a[0], a[1]);
            h2 a23 = pkrtz(a[2], a[3]);
            h2 b01 = pkrtz(b[0], b[1]);
            h2 b23 = pkrtz(b[2], b[3]);
            lw[j] = (h4){a01[0], a01[1], a23[0], a23[1]};
            lq[j] = (h4){b01[0], b01[1], b23[0], b23[1]};
        }
    }

    // Load + convert this wave's 4 x-rows before the barrier (overlaps
    // other waves' staging). 16 VGPRs resident.
    h8 xv[4];
    #pragma unroll
    for (int b = 0; b < 4; ++b) {
        const float* xr = x + (size_t)(b0 + b) * INN + i0;
        f4 lo = *(const f4*)xr;
        f4 hi = *(const f4*)(xr + 4);
        h2 p0 = pkrtz(lo[0], lo[1]);
        h2 p1 = pkrtz(lo[2], lo[3]);
        h2 p2 = pkrtz(hi[0], hi[1]);
        h2 p3 = pkrtz(hi[2], hi[3]);
        xv[b] = (h8){p0[0], p0[1], p1[0], p1[1], p2[0], p2[1], p3[0], p3[1]};
    }

    __syncthreads();

    float acc[4];
    #pragma unroll
    for (int b = 0; b < 4; ++b) acc[b] = 0.0f;

    const h2 one = {(_Float16)1.0f, (_Float16)1.0f};

    // unroll 2: two m's of fragments live (16 regs), not all 8 (R3 lesson).
    #pragma unroll 2
    for (int m = 0; m < MM; ++m) {
        const h8 w8 = *(const h8*)(lds_w + m * INN + i0);
        const h8 q8 = *(const h8*)(lds_q + m * INN + i0);
        #pragma unroll
        for (int b = 0; b < 4; ++b) {
            #pragma unroll
            for (int p = 0; p < 4; ++p) {
                // Each h2 is one VGPR of the h8 — no repack.
                h2 xx = {xv[b][2 * p], xv[b][2 * p + 1]};
                h2 ww = {w8[2 * p], w8[2 * p + 1]};
                h2 qq = {q8[2 * p], q8[2 * p + 1]};
                // v_pk_fma_f16 + v_pk_max_f16 + v_dot2_f32_f16
                h2 t = __builtin_elementwise_fma(xx, ww, -qq);
                t = __builtin_elementwise_max(t, (h2)(_Float16)0.0f);
#if __has_builtin(__builtin_amdgcn_fdot2)
                acc[b] = __builtin_amdgcn_fdot2(t, one, acc[b], false);
#else
                acc[b] += (float)t[0] + (float)t[1];
#endif
            }
        }
    }

    // Butterfly-reduce each acc[b] across 64 lanes; lane b writes (b0+b, o).
    #pragma unroll
    for (int b = 0; b < 4; ++b) {
        float v = acc[b];
        v += __shfl_xor(v, 1, 64);
        v += __shfl_xor(v, 2, 64);
        v += __shfl_xor(v, 4, 64);
        v += __shfl_xor(v, 8, 64);
        v += __shfl_xor(v, 16, 64);
        v += __shfl_xor(v, 32, 64);
        if (lane == b) {
            float r = 0.25f * v - 0.05f;   // K*K*S - K*QS
            out[(size_t)(b0 + b) * OUTN + o] = fmaxf(r, 0.0f);
        }
    }
}

extern "C" void kernel_launch(void* const* d_in, const int* in_sizes, int n_in,
                              void* d_out, int out_size, void* d_ws, size_t ws_size,
                              hipStream_t stream) {
    const float* x = (const float*)d_in[0];
    const float* W = (const float*)d_in[1];
    const float* q = (const float*)d_in[2];
    float* out = (float*)d_out;
    dim3 grid(OUTN * 32);   // 128 o * 32 b-groups = 4096 blocks
    dim3 block(256);
    dnm_kernel<<<grid, block, 0, stream>>>(x, W, q, out);
}